// Round 1
// baseline (2114.267 us; speedup 1.0000x reference)
//
#include <hip/hip_runtime.h>
#include <hip/hip_bf16.h>
#include <math.h>

#define NROWS 16384
#define DD 4096

typedef __attribute__((ext_vector_type(8))) short short8;
typedef __attribute__((ext_vector_type(4))) float f32x4;

typedef const __attribute__((address_space(1))) void* gas_cvp;
typedef __attribute__((address_space(3))) void* las_vp;

__device__ __forceinline__ void gload_lds16(const void* g, void* l) {
  __builtin_amdgcn_global_load_lds((gas_cvp)g, (las_vp)l, 16, 0, 0);
}

// ---------------- FFT magnitude + row-max normalize -> bf16 A ----------------
__global__ __launch_bounds__(256) void k_fftmag(const float* __restrict__ x,
                                                __hip_bfloat16* __restrict__ A) {
  __shared__ float re[DD];
  __shared__ float im[DD];
  __shared__ float twr[DD / 2];
  __shared__ float twi[DD / 2];
  const int t = threadIdx.x;
  const size_t row = blockIdx.x;
  const float* __restrict__ xr = x + row * DD;

  // twiddle table: tw[k] = exp(-2*pi*i*k/4096), k = 0..2047
  #pragma unroll
  for (int u = 0; u < 8; ++u) {
    int k = t + u * 256;
    float s, c;
    sincosf(-6.283185307179586f * (float)k / (float)DD, &s, &c);
    twr[k] = c; twi[k] = s;
  }
  // load with bit-reversal (12-bit)
  #pragma unroll
  for (int u = 0; u < 16; ++u) {
    int j = t + u * 256;
    int bj = (int)(__brev((unsigned)j) >> 20);
    re[bj] = xr[j];
    im[bj] = 0.0f;
  }
  __syncthreads();
  for (int s = 1; s <= 12; ++s) {
    const int half = 1 << (s - 1);
    const int tsh = 12 - s;  // twiddle index stride = 2048/half = 1<<(12-s)
    #pragma unroll
    for (int u = 0; u < 8; ++u) {
      int b = t + u * 256;
      int pos = b & (half - 1);
      int i0 = ((b >> (s - 1)) << s) + pos;
      int i1 = i0 + half;
      int ti = pos << tsh;
      float wr = twr[ti], wi = twi[ti];
      float ar = re[i1], ai = im[i1];
      float tr = wr * ar - wi * ai;
      float tq = wr * ai + wi * ar;
      float ur = re[i0], ui = im[i0];
      re[i1] = ur - tr; im[i1] = ui - tq;
      re[i0] = ur + tr; im[i0] = ui + tq;
    }
    __syncthreads();
  }
  // magnitude + row max
  float mx = 0.0f;
  float mag[16];
  #pragma unroll
  for (int u = 0; u < 16; ++u) {
    int j = t + u * 256;
    float a = re[j], b = im[j];
    float m = sqrtf(a * a + b * b);
    mag[u] = m;
    mx = fmaxf(mx, m);
  }
  #pragma unroll
  for (int off = 32; off > 0; off >>= 1) mx = fmaxf(mx, __shfl_xor(mx, off));
  __shared__ float wmax[4];
  if ((t & 63) == 0) wmax[t >> 6] = mx;
  __syncthreads();
  mx = fmaxf(fmaxf(wmax[0], wmax[1]), fmaxf(wmax[2], wmax[3]));
  const float inv = 1.0f / (mx + 1e-6f);
  #pragma unroll
  for (int u = 0; u < 16; ++u) {
    int j = t + u * 256;
    A[row * DD + j] = __float2bfloat16(mag[u] * inv);
  }
}

// ---------------- Sinkhorn: log_P = w - r_i - c_j (outer form) ----------------
__device__ __forceinline__ void lse_acc(float& m, float& s, float v) {
  float nm = fmaxf(m, v);
  s = s * __expf(m - nm) + __expf(v - nm);
  m = nm;
}
__device__ __forceinline__ void lse_merge(float& m, float& s, float m2, float s2) {
  float nm = fmaxf(m, m2);
  s = s * __expf(m - nm) + s2 * __expf(m2 - nm);
  m = nm;
}

__global__ void k_zero(float* __restrict__ p, int n) {
  int i = blockIdx.x * 256 + threadIdx.x;
  if (i < n) p[i] = 0.0f;
}

// r_i = lse_j(w_ij - c_j); one block per row
__global__ __launch_bounds__(256) void k_row_lse(const float* __restrict__ w,
                                                 const float* __restrict__ c,
                                                 float* __restrict__ r) {
  const int i = blockIdx.x;
  const int t = threadIdx.x;
  const float* __restrict__ wr = w + (size_t)i * DD;
  float m = -INFINITY, s = 0.0f;
  #pragma unroll
  for (int u = 0; u < 16; ++u) {
    int j = t + u * 256;
    lse_acc(m, s, wr[j] - c[j]);
  }
  #pragma unroll
  for (int off = 32; off > 0; off >>= 1) {
    float m2 = __shfl_xor(m, off);
    float s2 = __shfl_xor(s, off);
    lse_merge(m, s, m2, s2);
  }
  __shared__ float sm[4], ss[4];
  if ((t & 63) == 0) { sm[t >> 6] = m; ss[t >> 6] = s; }
  __syncthreads();
  if (t == 0) {
    float M = sm[0], S = ss[0];
    lse_merge(M, S, sm[1], ss[1]);
    lse_merge(M, S, sm[2], ss[2]);
    lse_merge(M, S, sm[3], ss[3]);
    r[i] = M + __logf(S);
  }
}

// partial col lse over 128-row chunks; fully coalesced (thread = column)
__global__ __launch_bounds__(256) void k_col_partial(const float* __restrict__ w,
                                                     const float* __restrict__ r,
                                                     float* __restrict__ pm,
                                                     float* __restrict__ ps) {
  const int j = blockIdx.x * 256 + threadIdx.x;
  const int i0 = blockIdx.y * 128;
  float m = -INFINITY, s = 0.0f;
  #pragma unroll 4
  for (int ii = 0; ii < 128; ++ii) {
    const int i = i0 + ii;
    lse_acc(m, s, w[(size_t)i * DD + j] - r[i]);
  }
  pm[(size_t)blockIdx.y * DD + j] = m;
  ps[(size_t)blockIdx.y * DD + j] = s;
}

__global__ __launch_bounds__(256) void k_col_final(const float* __restrict__ pm,
                                                   const float* __restrict__ ps,
                                                   float* __restrict__ c) {
  const int j = blockIdx.x * 256 + threadIdx.x;
  float m = -INFINITY, s = 0.0f;
  #pragma unroll 4
  for (int k = 0; k < 32; ++k) {
    lse_merge(m, s, pm[(size_t)k * DD + j], ps[(size_t)k * DD + j]);
  }
  c[j] = m + __logf(s);
}

// P = exp(w - r - c) -> f32 out; also bf16 P^T into ws (LDS tiled transpose)
__global__ __launch_bounds__(256) void k_pfinal(const float* __restrict__ w,
                                                const float* __restrict__ r,
                                                const float* __restrict__ c,
                                                float* __restrict__ P,
                                                __hip_bfloat16* __restrict__ Bt) {
  __shared__ __hip_bfloat16 tile[64][66];
  const int t = threadIdx.x;
  const int tx = t & 63;
  const int ty = t >> 6;  // 0..3
  const int bi = blockIdx.y * 64;
  const int bj = blockIdx.x * 64;
  #pragma unroll
  for (int p = 0; p < 16; ++p) {
    int rr = p * 4 + ty;
    int gi = bi + rr, gj = bj + tx;
    float v = __expf(w[(size_t)gi * DD + gj] - r[gi] - c[gj]);
    P[(size_t)gi * DD + gj] = v;
    tile[rr][tx] = __float2bfloat16(v);
  }
  __syncthreads();
  #pragma unroll
  for (int p = 0; p < 16; ++p) {
    int rr = p * 4 + ty;  // local col of P-tile = row of Bt-tile
    int gj = bj + rr;
    int gi = bi + tx;
    Bt[(size_t)gj * DD + gi] = tile[tx][rr];
  }
}

// ---------------- GEMM: C[16384][4096] = A(bf16) @ P, B^T layout ----------------
#define BM 128
#define BN 128
#define BK 32

__global__ __launch_bounds__(256) void k_gemm(const __hip_bfloat16* __restrict__ A,
                                              const __hip_bfloat16* __restrict__ Bt,
                                              float* __restrict__ C) {
  __shared__ __hip_bfloat16 As[BM * BK];
  __shared__ __hip_bfloat16 Bs[BN * BK];
  const int tid = threadIdx.x;
  const int lane = tid & 63;
  const int wid = tid >> 6;
  const int wr = wid >> 1, wc = wid & 1;

  // XCD-aware swizzle (4096 blocks, divisible by 8 -> bijective)
  const int bid = blockIdx.x;
  const int swz = (bid & 7) * 512 + (bid >> 3);
  const size_t brow = (size_t)(swz >> 5) * BM;   // 128 M-tiles
  const size_t bcol = (size_t)(swz & 31) * BN;   // 32 N-tiles

  const int ldrow = tid >> 2;        // 0..63
  const int ldcol = (tid & 3) * 8;   // bf16 elements (16B)

  f32x4 acc[4][4] = {};

  const int lr = lane & 15;
  const int lk = (lane >> 4) * 8;

  for (int kt = 0; kt < DD / BK; ++kt) {
    const int k0 = kt * BK;
    gload_lds16(&A[(brow + ldrow) * DD + k0 + ldcol], &As[ldrow * BK + ldcol]);
    gload_lds16(&A[(brow + 64 + ldrow) * DD + k0 + ldcol], &As[(64 + ldrow) * BK + ldcol]);
    gload_lds16(&Bt[(bcol + ldrow) * DD + k0 + ldcol], &Bs[ldrow * BK + ldcol]);
    gload_lds16(&Bt[(bcol + 64 + ldrow) * DD + k0 + ldcol], &Bs[(64 + ldrow) * BK + ldcol]);
    __syncthreads();
    short8 af[4], bf[4];
    #pragma unroll
    for (int m = 0; m < 4; ++m)
      af[m] = *reinterpret_cast<const short8*>(&As[(wr * 64 + m * 16 + lr) * BK + lk]);
    #pragma unroll
    for (int n = 0; n < 4; ++n)
      bf[n] = *reinterpret_cast<const short8*>(&Bs[(wc * 64 + n * 16 + lr) * BK + lk]);
    #pragma unroll
    for (int m = 0; m < 4; ++m) {
      #pragma unroll
      for (int n = 0; n < 4; ++n) {
        acc[m][n] = __builtin_amdgcn_mfma_f32_16x16x32_bf16(af[m], bf[n], acc[m][n], 0, 0, 0);
      }
    }
    __syncthreads();
  }
  // epilogue: C/D layout col = lane&15, row = (lane>>4)*4 + reg
  const int orow = (lane >> 4) * 4;
  const int ocol = lane & 15;
  #pragma unroll
  for (int m = 0; m < 4; ++m) {
    #pragma unroll
    for (int n = 0; n < 4; ++n) {
      #pragma unroll
      for (int jj = 0; jj < 4; ++jj) {
        size_t rrow = brow + (size_t)wr * 64 + m * 16 + orow + jj;
        size_t ccol = bcol + (size_t)wc * 64 + n * 16 + ocol;
        C[rrow * DD + ccol] = acc[m][n][jj];
      }
    }
  }
}

extern "C" void kernel_launch(void* const* d_in, const int* in_sizes, int n_in,
                              void* d_out, int out_size, void* d_ws, size_t ws_size,
                              hipStream_t stream) {
  const float* x = (const float*)d_in[0];
  const float* w = (const float*)d_in[1];
  float* outMM = (float*)d_out;                        // [16384][4096]
  float* outP = (float*)d_out + (size_t)NROWS * DD;    // [4096][4096]

  char* ws = (char*)d_ws;
  __hip_bfloat16* A = (__hip_bfloat16*)ws;                                   // 128MB
  __hip_bfloat16* Bt = (__hip_bfloat16*)(ws + (size_t)NROWS * DD * 2);       // 32MB
  float* r = (float*)(ws + (size_t)NROWS * DD * 2 + (size_t)DD * DD * 2);
  float* c = r + DD;
  float* pm = c + DD;
  float* ps = pm + 32 * DD;

  k_zero<<<DD / 256, 256, 0, stream>>>(c, DD);
  k_fftmag<<<NROWS, 256, 0, stream>>>(x, A);
  for (int it = 0; it < 5; ++it) {
    k_row_lse<<<DD, 256, 0, stream>>>(w, c, r);
    k_col_partial<<<dim3(16, 32), 256, 0, stream>>>(w, r, pm, ps);
    k_col_final<<<DD / 256, 256, 0, stream>>>(pm, ps, c);
  }
  k_pfinal<<<dim3(64, 64), 256, 0, stream>>>(w, r, c, outP, Bt);
  k_gemm<<<4096, 256, 0, stream>>>(A, Bt, outMM);
}

// Round 2
// 1329.923 us; speedup vs baseline: 1.5898x; 1.5898x over previous
//
#include <hip/hip_runtime.h>
#include <hip/hip_bf16.h>
#include <math.h>

#define NROWS 16384
#define DD 4096

typedef __attribute__((ext_vector_type(8))) short short8;
typedef __attribute__((ext_vector_type(4))) float f32x4;

typedef const __attribute__((address_space(1))) void* gas_cvp;
typedef __attribute__((address_space(3))) void* las_vp;

__device__ __forceinline__ void gload_lds16(const void* g, void* l) {
  __builtin_amdgcn_global_load_lds((gas_cvp)g, (las_vp)l, 16, 0, 0);
}

// ---------------- 16-point FFT in registers (two radix-4 stages) ----------------
__device__ __forceinline__ void dft4(float ar, float ai, float br, float bi,
                                     float cr, float ci, float dr, float di,
                                     float& y0r, float& y0i, float& y1r, float& y1i,
                                     float& y2r, float& y2i, float& y3r, float& y3i) {
  float t0r = ar + cr, t0i = ai + ci;
  float t1r = ar - cr, t1i = ai - ci;
  float t2r = br + dr, t2i = bi + di;
  float t3r = br - dr, t3i = bi - di;
  y0r = t0r + t2r; y0i = t0i + t2i;
  y2r = t0r - t2r; y2i = t0i - t2i;
  // -i * t3 = (t3i, -t3r)
  y1r = t1r + t3i; y1i = t1i - t3r;
  y3r = t1r - t3i; y3i = t1i + t3r;
}

#define C16_1 0.9238795325112867f
#define S16_1 0.3826834323650898f
#define C16_2 0.7071067811865476f

__device__ __forceinline__ void fft16(float* xr, float* xi) {
  // W16^k = cos - i sin, k = 0..9 (only 0..9 used: n2*k1 <= 9)
  const float W16R[10] = {1.f,  C16_1,  C16_2,  S16_1, 0.f, -S16_1, -C16_2, -C16_1, -1.f, -C16_1};
  const float W16I[10] = {0.f, -S16_1, -C16_2, -C16_1, -1.f, -C16_1, -C16_2, -S16_1, 0.f,  S16_1};
  float gr[16], gi[16];
  #pragma unroll
  for (int n2 = 0; n2 < 4; ++n2) {
    dft4(xr[n2], xi[n2], xr[4 + n2], xi[4 + n2], xr[8 + n2], xi[8 + n2], xr[12 + n2], xi[12 + n2],
         gr[0 * 4 + n2], gi[0 * 4 + n2], gr[1 * 4 + n2], gi[1 * 4 + n2],
         gr[2 * 4 + n2], gi[2 * 4 + n2], gr[3 * 4 + n2], gi[3 * 4 + n2]);
  }
  #pragma unroll
  for (int k1 = 1; k1 < 4; ++k1) {
    #pragma unroll
    for (int n2 = 1; n2 < 4; ++n2) {
      const float wr = W16R[k1 * n2], wi = W16I[k1 * n2];
      float a = gr[k1 * 4 + n2], b = gi[k1 * 4 + n2];
      gr[k1 * 4 + n2] = a * wr - b * wi;
      gi[k1 * 4 + n2] = a * wi + b * wr;
    }
  }
  #pragma unroll
  for (int k1 = 0; k1 < 4; ++k1) {
    dft4(gr[k1 * 4 + 0], gi[k1 * 4 + 0], gr[k1 * 4 + 1], gi[k1 * 4 + 1],
         gr[k1 * 4 + 2], gi[k1 * 4 + 2], gr[k1 * 4 + 3], gi[k1 * 4 + 3],
         xr[k1 + 0], xi[k1 + 0], xr[k1 + 4], xi[k1 + 4],
         xr[k1 + 8], xi[k1 + 8], xr[k1 + 12], xi[k1 + 12]);
  }
}

// ---------------- FFT magnitude + row-max normalize -> bf16 A ----------------
// 4096 = 16 x 16 x 16, three register fft16 passes, two LDS exchanges.
__global__ __launch_bounds__(256) void k_fftmag(const float* __restrict__ x,
                                                __hip_bfloat16* __restrict__ A) {
  __shared__ float lre[16 * 272];
  __shared__ float lim[16 * 272];
  const int t = threadIdx.x;
  const size_t row = blockIdx.x;
  const float* __restrict__ xg = x + row * DD;

  float xr[16], xi[16];

  // ---- pass 1: n2 = t; A1[k1] = DFT16 over n1 of x[n1*256 + t] ----
  #pragma unroll
  for (int n1 = 0; n1 < 16; ++n1) {
    xr[n1] = xg[n1 * 256 + t];
    xi[n1] = 0.0f;
  }
  fft16(xr, xi);
  // twiddle W4096^{t*k1}
  {
    float w1r, w1i;
    __sincosf(-6.283185307179586f * (float)t / 4096.0f, &w1i, &w1r);
    float wr = 1.f, wi = 0.f;
    #pragma unroll
    for (int k = 1; k < 16; ++k) {
      float nr = wr * w1r - wi * w1i;
      float ni = wr * w1i + wi * w1r;
      wr = nr; wi = ni;
      float a = xr[k], b = xi[k];
      xr[k] = a * wr - b * wi;
      xi[k] = a * wi + b * wr;
    }
  }
  // exchange 1: [k1][t], stride 272 (= 16 mod 32 -> parity-split banks, 2-way)
  #pragma unroll
  for (int k1 = 0; k1 < 16; ++k1) {
    lre[k1 * 272 + t] = xr[k1];
    lim[k1 * 272 + t] = xi[k1];
  }
  __syncthreads();

  // ---- pass 2: thread = (k1, m2); DFT16 over m1 of B[k1][m1*16+m2] ----
  const int k1 = t >> 4;
  const int m2 = t & 15;
  #pragma unroll
  for (int m1 = 0; m1 < 16; ++m1) {
    xr[m1] = lre[k1 * 272 + m1 * 16 + m2];
    xi[m1] = lim[k1 * 272 + m1 * 16 + m2];
  }
  fft16(xr, xi);
  // twiddle W256^{m2*j1}
  {
    float w1r, w1i;
    __sincosf(-6.283185307179586f * (float)m2 / 256.0f, &w1i, &w1r);
    float wr = 1.f, wi = 0.f;
    #pragma unroll
    for (int k = 1; k < 16; ++k) {
      float nr = wr * w1r - wi * w1i;
      float ni = wr * w1i + wi * w1r;
      wr = nr; wi = ni;
      float a = xr[k], b = xi[k];
      xr[k] = a * wr - b * wi;
      xi[k] = a * wi + b * wr;
    }
  }
  __syncthreads();  // all reads of exchange-1 done before overwrite
  // exchange 2: addr = j1*256 + k1*16 + (m2 ^ j1)  (XOR swizzle, 2-way both sides)
  #pragma unroll
  for (int j1 = 0; j1 < 16; ++j1) {
    lre[j1 * 256 + k1 * 16 + (m2 ^ j1)] = xr[j1];
    lim[j1 * 256 + k1 * 16 + (m2 ^ j1)] = xi[j1];
  }
  __syncthreads();

  // ---- pass 3: thread = (k1, j1); DFT16 over m2 -> X[k1 + 16*j1 + 256*j2] ----
  const int j1 = t & 15;  // k1 = t >> 4 (same)
  #pragma unroll
  for (int mm = 0; mm < 16; ++mm) {
    xr[mm] = lre[j1 * 256 + k1 * 16 + (mm ^ j1)];
    xi[mm] = lim[j1 * 256 + k1 * 16 + (mm ^ j1)];
  }
  fft16(xr, xi);

  // magnitude + row max
  float mag[16];
  float mx = 0.0f;
  #pragma unroll
  for (int j2 = 0; j2 < 16; ++j2) {
    float m = sqrtf(xr[j2] * xr[j2] + xi[j2] * xi[j2]);
    mag[j2] = m;
    mx = fmaxf(mx, m);
  }
  #pragma unroll
  for (int off = 32; off > 0; off >>= 1) mx = fmaxf(mx, __shfl_xor(mx, off));
  __shared__ float wmax[4];
  if ((t & 63) == 0) wmax[t >> 6] = mx;
  __syncthreads();
  mx = fmaxf(fmaxf(wmax[0], wmax[1]), fmaxf(wmax[2], wmax[3]));
  const float inv = 1.0f / (mx + 1e-6f);
  #pragma unroll
  for (int j2 = 0; j2 < 16; ++j2) {
    A[row * DD + (size_t)(k1 + 16 * j1 + 256 * j2)] = __float2bfloat16(mag[j2] * inv);
  }
}

// ---------------- Sinkhorn: log_P = w - r_i - c_j (outer form) ----------------
__device__ __forceinline__ void lse_acc(float& m, float& s, float v) {
  float nm = fmaxf(m, v);
  s = s * __expf(m - nm) + __expf(v - nm);
  m = nm;
}
__device__ __forceinline__ void lse_merge(float& m, float& s, float m2, float s2) {
  float nm = fmaxf(m, m2);
  s = s * __expf(m - nm) + s2 * __expf(m2 - nm);
  m = nm;
}

__global__ void k_zero(float* __restrict__ p, int n) {
  int i = blockIdx.x * 256 + threadIdx.x;
  if (i < n) p[i] = 0.0f;
}

// r_i = lse_j(w_ij - c_j); one block per row
__global__ __launch_bounds__(256) void k_row_lse(const float* __restrict__ w,
                                                 const float* __restrict__ c,
                                                 float* __restrict__ r) {
  const int i = blockIdx.x;
  const int t = threadIdx.x;
  const float* __restrict__ wr = w + (size_t)i * DD;
  float m = -INFINITY, s = 0.0f;
  #pragma unroll
  for (int u = 0; u < 16; ++u) {
    int j = t + u * 256;
    lse_acc(m, s, wr[j] - c[j]);
  }
  #pragma unroll
  for (int off = 32; off > 0; off >>= 1) {
    float m2 = __shfl_xor(m, off);
    float s2 = __shfl_xor(s, off);
    lse_merge(m, s, m2, s2);
  }
  __shared__ float sm[4], ss[4];
  if ((t & 63) == 0) { sm[t >> 6] = m; ss[t >> 6] = s; }
  __syncthreads();
  if (t == 0) {
    float M = sm[0], S = ss[0];
    lse_merge(M, S, sm[1], ss[1]);
    lse_merge(M, S, sm[2], ss[2]);
    lse_merge(M, S, sm[3], ss[3]);
    r[i] = M + __logf(S);
  }
}

// partial col lse over 128-row chunks; fully coalesced (thread = column)
__global__ __launch_bounds__(256) void k_col_partial(const float* __restrict__ w,
                                                     const float* __restrict__ r,
                                                     float* __restrict__ pm,
                                                     float* __restrict__ ps) {
  const int j = blockIdx.x * 256 + threadIdx.x;
  const int i0 = blockIdx.y * 128;
  float m = -INFINITY, s = 0.0f;
  #pragma unroll 4
  for (int ii = 0; ii < 128; ++ii) {
    const int i = i0 + ii;
    lse_acc(m, s, w[(size_t)i * DD + j] - r[i]);
  }
  pm[(size_t)blockIdx.y * DD + j] = m;
  ps[(size_t)blockIdx.y * DD + j] = s;
}

__global__ __launch_bounds__(256) void k_col_final(const float* __restrict__ pm,
                                                   const float* __restrict__ ps,
                                                   float* __restrict__ c) {
  const int j = blockIdx.x * 256 + threadIdx.x;
  float m = -INFINITY, s = 0.0f;
  #pragma unroll 4
  for (int k = 0; k < 32; ++k) {
    lse_merge(m, s, pm[(size_t)k * DD + j], ps[(size_t)k * DD + j]);
  }
  c[j] = m + __logf(s);
}

// P = exp(w - r - c) -> f32 out; also bf16 P^T into ws (LDS tiled transpose)
__global__ __launch_bounds__(256) void k_pfinal(const float* __restrict__ w,
                                                const float* __restrict__ r,
                                                const float* __restrict__ c,
                                                float* __restrict__ P,
                                                __hip_bfloat16* __restrict__ Bt) {
  __shared__ __hip_bfloat16 tile[64][66];
  const int t = threadIdx.x;
  const int tx = t & 63;
  const int ty = t >> 6;  // 0..3
  const int bi = blockIdx.y * 64;
  const int bj = blockIdx.x * 64;
  #pragma unroll
  for (int p = 0; p < 16; ++p) {
    int rr = p * 4 + ty;
    int gi = bi + rr, gj = bj + tx;
    float v = __expf(w[(size_t)gi * DD + gj] - r[gi] - c[gj]);
    P[(size_t)gi * DD + gj] = v;
    tile[rr][tx] = __float2bfloat16(v);
  }
  __syncthreads();
  #pragma unroll
  for (int p = 0; p < 16; ++p) {
    int rr = p * 4 + ty;  // local col of P-tile = row of Bt-tile
    int gj = bj + rr;
    int gi = bi + tx;
    Bt[(size_t)gj * DD + gi] = tile[tx][rr];
  }
}

// ---------------- GEMM: C[16384][4096] = A(bf16) @ P, B^T layout ----------------
#define BM 128
#define BN 128
#define BK 32

__global__ __launch_bounds__(256) void k_gemm(const __hip_bfloat16* __restrict__ A,
                                              const __hip_bfloat16* __restrict__ Bt,
                                              float* __restrict__ C) {
  __shared__ __hip_bfloat16 As[BM * BK];
  __shared__ __hip_bfloat16 Bs[BN * BK];
  const int tid = threadIdx.x;
  const int lane = tid & 63;
  const int wid = tid >> 6;
  const int wr = wid >> 1, wc = wid & 1;

  // XCD-aware swizzle (4096 blocks, divisible by 8 -> bijective)
  const int bid = blockIdx.x;
  const int swz = (bid & 7) * 512 + (bid >> 3);
  const size_t brow = (size_t)(swz >> 5) * BM;   // 128 M-tiles
  const size_t bcol = (size_t)(swz & 31) * BN;   // 32 N-tiles

  const int ldrow = tid >> 2;        // 0..63
  const int ldcol = (tid & 3) * 8;   // bf16 elements (16B)

  f32x4 acc[4][4] = {};

  const int lr = lane & 15;
  const int lk = (lane >> 4) * 8;

  for (int kt = 0; kt < DD / BK; ++kt) {
    const int k0 = kt * BK;
    gload_lds16(&A[(brow + ldrow) * DD + k0 + ldcol], &As[ldrow * BK + ldcol]);
    gload_lds16(&A[(brow + 64 + ldrow) * DD + k0 + ldcol], &As[(64 + ldrow) * BK + ldcol]);
    gload_lds16(&Bt[(bcol + ldrow) * DD + k0 + ldcol], &Bs[ldrow * BK + ldcol]);
    gload_lds16(&Bt[(bcol + 64 + ldrow) * DD + k0 + ldcol], &Bs[(64 + ldrow) * BK + ldcol]);
    __syncthreads();
    short8 af[4], bf[4];
    #pragma unroll
    for (int m = 0; m < 4; ++m)
      af[m] = *reinterpret_cast<const short8*>(&As[(wr * 64 + m * 16 + lr) * BK + lk]);
    #pragma unroll
    for (int n = 0; n < 4; ++n)
      bf[n] = *reinterpret_cast<const short8*>(&Bs[(wc * 64 + n * 16 + lr) * BK + lk]);
    #pragma unroll
    for (int m = 0; m < 4; ++m) {
      #pragma unroll
      for (int n = 0; n < 4; ++n) {
        acc[m][n] = __builtin_amdgcn_mfma_f32_16x16x32_bf16(af[m], bf[n], acc[m][n], 0, 0, 0);
      }
    }
    __syncthreads();
  }
  // epilogue: C/D layout col = lane&15, row = (lane>>4)*4 + reg
  const int orow = (lane >> 4) * 4;
  const int ocol = lane & 15;
  #pragma unroll
  for (int m = 0; m < 4; ++m) {
    #pragma unroll
    for (int n = 0; n < 4; ++n) {
      #pragma unroll
      for (int jj = 0; jj < 4; ++jj) {
        size_t rrow = brow + (size_t)wr * 64 + m * 16 + orow + jj;
        size_t ccol = bcol + (size_t)wc * 64 + n * 16 + ocol;
        C[rrow * DD + ccol] = acc[m][n][jj];
      }
    }
  }
}

extern "C" void kernel_launch(void* const* d_in, const int* in_sizes, int n_in,
                              void* d_out, int out_size, void* d_ws, size_t ws_size,
                              hipStream_t stream) {
  const float* x = (const float*)d_in[0];
  const float* w = (const float*)d_in[1];
  float* outMM = (float*)d_out;                        // [16384][4096]
  float* outP = (float*)d_out + (size_t)NROWS * DD;    // [4096][4096]

  char* ws = (char*)d_ws;
  __hip_bfloat16* A = (__hip_bfloat16*)ws;                                   // 128MB
  __hip_bfloat16* Bt = (__hip_bfloat16*)(ws + (size_t)NROWS * DD * 2);       // 32MB
  float* r = (float*)(ws + (size_t)NROWS * DD * 2 + (size_t)DD * DD * 2);
  float* c = r + DD;
  float* pm = c + DD;
  float* ps = pm + 32 * DD;

  k_zero<<<DD / 256, 256, 0, stream>>>(c, DD);
  k_fftmag<<<NROWS, 256, 0, stream>>>(x, A);
  for (int it = 0; it < 5; ++it) {
    k_row_lse<<<DD, 256, 0, stream>>>(w, c, r);
    k_col_partial<<<dim3(16, 32), 256, 0, stream>>>(w, r, pm, ps);
    k_col_final<<<DD / 256, 256, 0, stream>>>(pm, ps, c);
  }
  k_pfinal<<<dim3(64, 64), 256, 0, stream>>>(w, r, c, outP, Bt);
  k_gemm<<<4096, 256, 0, stream>>>(A, Bt, outMM);
}

// Round 3
// 845.136 us; speedup vs baseline: 2.5017x; 1.5736x over previous
//
#include <hip/hip_runtime.h>
#include <hip/hip_bf16.h>
#include <math.h>

#define NROWS 16384
#define DD 4096

typedef __attribute__((ext_vector_type(8))) short short8;
typedef __attribute__((ext_vector_type(4))) float f32x4;

typedef const __attribute__((address_space(1))) void* gas_cvp;
typedef __attribute__((address_space(3))) void* las_vp;

__device__ __forceinline__ void gload_lds16(const void* g, void* l) {
  __builtin_amdgcn_global_load_lds((gas_cvp)g, (las_vp)l, 16, 0, 0);
}

// ---------------- 16-point FFT in registers (two radix-4 stages) ----------------
__device__ __forceinline__ void dft4(float ar, float ai, float br, float bi,
                                     float cr, float ci, float dr, float di,
                                     float& y0r, float& y0i, float& y1r, float& y1i,
                                     float& y2r, float& y2i, float& y3r, float& y3i) {
  float t0r = ar + cr, t0i = ai + ci;
  float t1r = ar - cr, t1i = ai - ci;
  float t2r = br + dr, t2i = bi + di;
  float t3r = br - dr, t3i = bi - di;
  y0r = t0r + t2r; y0i = t0i + t2i;
  y2r = t0r - t2r; y2i = t0i - t2i;
  y1r = t1r + t3i; y1i = t1i - t3r;
  y3r = t1r - t3i; y3i = t1i + t3r;
}

#define C16_1 0.9238795325112867f
#define S16_1 0.3826834323650898f
#define C16_2 0.7071067811865476f

__device__ __forceinline__ void fft16(float* xr, float* xi) {
  const float W16R[10] = {1.f,  C16_1,  C16_2,  S16_1, 0.f, -S16_1, -C16_2, -C16_1, -1.f, -C16_1};
  const float W16I[10] = {0.f, -S16_1, -C16_2, -C16_1, -1.f, -C16_1, -C16_2, -S16_1, 0.f,  S16_1};
  float gr[16], gi[16];
  #pragma unroll
  for (int n2 = 0; n2 < 4; ++n2) {
    dft4(xr[n2], xi[n2], xr[4 + n2], xi[4 + n2], xr[8 + n2], xi[8 + n2], xr[12 + n2], xi[12 + n2],
         gr[0 * 4 + n2], gi[0 * 4 + n2], gr[1 * 4 + n2], gi[1 * 4 + n2],
         gr[2 * 4 + n2], gi[2 * 4 + n2], gr[3 * 4 + n2], gi[3 * 4 + n2]);
  }
  #pragma unroll
  for (int k1 = 1; k1 < 4; ++k1) {
    #pragma unroll
    for (int n2 = 1; n2 < 4; ++n2) {
      const float wr = W16R[k1 * n2], wi = W16I[k1 * n2];
      float a = gr[k1 * 4 + n2], b = gi[k1 * 4 + n2];
      gr[k1 * 4 + n2] = a * wr - b * wi;
      gi[k1 * 4 + n2] = a * wi + b * wr;
    }
  }
  #pragma unroll
  for (int k1 = 0; k1 < 4; ++k1) {
    dft4(gr[k1 * 4 + 0], gi[k1 * 4 + 0], gr[k1 * 4 + 1], gi[k1 * 4 + 1],
         gr[k1 * 4 + 2], gi[k1 * 4 + 2], gr[k1 * 4 + 3], gi[k1 * 4 + 3],
         xr[k1 + 0], xi[k1 + 0], xr[k1 + 4], xi[k1 + 4],
         xr[k1 + 8], xi[k1 + 8], xr[k1 + 12], xi[k1 + 12]);
  }
}

// ---------------- FFT magnitude + row-max normalize -> bf16 A ----------------
__global__ __launch_bounds__(256) void k_fftmag(const float* __restrict__ x,
                                                __hip_bfloat16* __restrict__ A) {
  __shared__ float lre[16 * 272];
  __shared__ float lim[16 * 272];
  const int t = threadIdx.x;
  const size_t row = blockIdx.x;
  const float* __restrict__ xg = x + row * DD;

  float xr[16], xi[16];

  #pragma unroll
  for (int n1 = 0; n1 < 16; ++n1) {
    xr[n1] = xg[n1 * 256 + t];
    xi[n1] = 0.0f;
  }
  fft16(xr, xi);
  {
    float w1r, w1i;
    __sincosf(-6.283185307179586f * (float)t / 4096.0f, &w1i, &w1r);
    float wr = 1.f, wi = 0.f;
    #pragma unroll
    for (int k = 1; k < 16; ++k) {
      float nr = wr * w1r - wi * w1i;
      float ni = wr * w1i + wi * w1r;
      wr = nr; wi = ni;
      float a = xr[k], b = xi[k];
      xr[k] = a * wr - b * wi;
      xi[k] = a * wi + b * wr;
    }
  }
  #pragma unroll
  for (int k1 = 0; k1 < 16; ++k1) {
    lre[k1 * 272 + t] = xr[k1];
    lim[k1 * 272 + t] = xi[k1];
  }
  __syncthreads();

  const int k1 = t >> 4;
  const int m2 = t & 15;
  #pragma unroll
  for (int m1 = 0; m1 < 16; ++m1) {
    xr[m1] = lre[k1 * 272 + m1 * 16 + m2];
    xi[m1] = lim[k1 * 272 + m1 * 16 + m2];
  }
  fft16(xr, xi);
  {
    float w1r, w1i;
    __sincosf(-6.283185307179586f * (float)m2 / 256.0f, &w1i, &w1r);
    float wr = 1.f, wi = 0.f;
    #pragma unroll
    for (int k = 1; k < 16; ++k) {
      float nr = wr * w1r - wi * w1i;
      float ni = wr * w1i + wi * w1r;
      wr = nr; wi = ni;
      float a = xr[k], b = xi[k];
      xr[k] = a * wr - b * wi;
      xi[k] = a * wi + b * wr;
    }
  }
  __syncthreads();
  #pragma unroll
  for (int j1 = 0; j1 < 16; ++j1) {
    lre[j1 * 256 + k1 * 16 + (m2 ^ j1)] = xr[j1];
    lim[j1 * 256 + k1 * 16 + (m2 ^ j1)] = xi[j1];
  }
  __syncthreads();

  const int j1 = t & 15;
  #pragma unroll
  for (int mm = 0; mm < 16; ++mm) {
    xr[mm] = lre[j1 * 256 + k1 * 16 + (mm ^ j1)];
    xi[mm] = lim[j1 * 256 + k1 * 16 + (mm ^ j1)];
  }
  fft16(xr, xi);

  float mag[16];
  float mx = 0.0f;
  #pragma unroll
  for (int j2 = 0; j2 < 16; ++j2) {
    float m = sqrtf(xr[j2] * xr[j2] + xi[j2] * xi[j2]);
    mag[j2] = m;
    mx = fmaxf(mx, m);
  }
  #pragma unroll
  for (int off = 32; off > 0; off >>= 1) mx = fmaxf(mx, __shfl_xor(mx, off));
  __shared__ float wmax[4];
  if ((t & 63) == 0) wmax[t >> 6] = mx;
  __syncthreads();
  mx = fmaxf(fmaxf(wmax[0], wmax[1]), fmaxf(wmax[2], wmax[3]));
  const float inv = 1.0f / (mx + 1e-6f);
  #pragma unroll
  for (int j2 = 0; j2 < 16; ++j2) {
    A[row * DD + (size_t)(k1 + 16 * j1 + 256 * j2)] = __float2bfloat16(mag[j2] * inv);
  }
}

// ---------------- Sinkhorn: log_P = w - r_i - c_j (outer form) ----------------
__device__ __forceinline__ void lse_acc(float& m, float& s, float v) {
  float nm = fmaxf(m, v);
  s = s * __expf(m - nm) + __expf(v - nm);
  m = nm;
}
__device__ __forceinline__ void lse_merge(float& m, float& s, float m2, float s2) {
  float nm = fmaxf(m, m2);
  s = s * __expf(m - nm) + s2 * __expf(m2 - nm);
  m = nm;
}

__global__ void k_zero(float* __restrict__ p, int n) {
  int i = blockIdx.x * 256 + threadIdx.x;
  if (i < n) p[i] = 0.0f;
}

__global__ __launch_bounds__(256) void k_row_lse(const float* __restrict__ w,
                                                 const float* __restrict__ c,
                                                 float* __restrict__ r) {
  const int i = blockIdx.x;
  const int t = threadIdx.x;
  const float* __restrict__ wr = w + (size_t)i * DD;
  float m = -INFINITY, s = 0.0f;
  #pragma unroll
  for (int u = 0; u < 16; ++u) {
    int j = t + u * 256;
    lse_acc(m, s, wr[j] - c[j]);
  }
  #pragma unroll
  for (int off = 32; off > 0; off >>= 1) {
    float m2 = __shfl_xor(m, off);
    float s2 = __shfl_xor(s, off);
    lse_merge(m, s, m2, s2);
  }
  __shared__ float sm[4], ss[4];
  if ((t & 63) == 0) { sm[t >> 6] = m; ss[t >> 6] = s; }
  __syncthreads();
  if (t == 0) {
    float M = sm[0], S = ss[0];
    lse_merge(M, S, sm[1], ss[1]);
    lse_merge(M, S, sm[2], ss[2]);
    lse_merge(M, S, sm[3], ss[3]);
    r[i] = M + __logf(S);
  }
}

__global__ __launch_bounds__(256) void k_col_partial(const float* __restrict__ w,
                                                     const float* __restrict__ r,
                                                     float* __restrict__ pm,
                                                     float* __restrict__ ps) {
  const int j = blockIdx.x * 256 + threadIdx.x;
  const int i0 = blockIdx.y * 128;
  float m = -INFINITY, s = 0.0f;
  #pragma unroll 4
  for (int ii = 0; ii < 128; ++ii) {
    const int i = i0 + ii;
    lse_acc(m, s, w[(size_t)i * DD + j] - r[i]);
  }
  pm[(size_t)blockIdx.y * DD + j] = m;
  ps[(size_t)blockIdx.y * DD + j] = s;
}

__global__ __launch_bounds__(256) void k_col_final(const float* __restrict__ pm,
                                                   const float* __restrict__ ps,
                                                   float* __restrict__ c) {
  const int j = blockIdx.x * 256 + threadIdx.x;
  float m = -INFINITY, s = 0.0f;
  #pragma unroll 4
  for (int k = 0; k < 32; ++k) {
    lse_merge(m, s, pm[(size_t)k * DD + j], ps[(size_t)k * DD + j]);
  }
  c[j] = m + __logf(s);
}

// P = exp(w - r - c) -> f32 out; also bf16 P^T into ws (LDS tiled transpose)
__global__ __launch_bounds__(256) void k_pfinal(const float* __restrict__ w,
                                                const float* __restrict__ r,
                                                const float* __restrict__ c,
                                                float* __restrict__ P,
                                                __hip_bfloat16* __restrict__ Bt) {
  __shared__ __hip_bfloat16 tile[64][66];
  const int t = threadIdx.x;
  const int tx = t & 63;
  const int ty = t >> 6;
  const int bi = blockIdx.y * 64;
  const int bj = blockIdx.x * 64;
  #pragma unroll
  for (int p = 0; p < 16; ++p) {
    int rr = p * 4 + ty;
    int gi = bi + rr, gj = bj + tx;
    float v = __expf(w[(size_t)gi * DD + gj] - r[gi] - c[gj]);
    P[(size_t)gi * DD + gj] = v;
    tile[rr][tx] = __float2bfloat16(v);
  }
  __syncthreads();
  #pragma unroll
  for (int p = 0; p < 16; ++p) {
    int rr = p * 4 + ty;
    int gj = bj + rr;
    int gi = bi + tx;
    Bt[(size_t)gj * DD + gi] = tile[tx][rr];
  }
}

// ---------------- GEMM: 256x256 tile, BK=64, 8-phase schedule (m201 template) --
// LDS map (bytes): A: [buf*32768 + ks*16384 + row*64 + col], rows 0..255, col 0..63
//                  B: 65536 + same. st_16x32 swizzle: col ^= ((row>>3)&1)<<5,
//                  applied on READ; staging pre-swizzles the GLOBAL source col.
__global__ __launch_bounds__(512, 2) void k_gemm256(const __hip_bfloat16* __restrict__ A,
                                                    const __hip_bfloat16* __restrict__ Bt,
                                                    float* __restrict__ C) {
  __shared__ alignas(16) char lds[131072];
  const int tid = threadIdx.x;
  const int lane = tid & 63;
  const int wid = tid >> 6;
  const int wm = wid >> 2;   // 0..1
  const int wn = wid & 3;    // 0..3

  // XCD-aware swizzle: 1024 wgs = 8 XCDs x 128 (bijective)
  const int bid = blockIdx.x;
  const int swz = (bid & 7) * 128 + (bid >> 3);
  const int mtile = swz >> 4;   // 0..63
  const int ntile = swz & 15;   // 0..15
  const size_t arow = (size_t)mtile * 256;
  const size_t brow = (size_t)ntile * 256;

  // staging: thread t covers (row = L*128 + t>>2, colbyte = (t&3)*16) of a
  // [256][32] bf16 half-tile; global source col pre-swizzled (rule #21).
  const int srow = tid >> 2;
  const int scolb = ((tid & 3) << 4) ^ (((tid >> 5) & 1) << 5);
  const __hip_bfloat16* gA = A + (arow + srow) * (size_t)DD + (scolb >> 1);
  const __hip_bfloat16* gB = Bt + (brow + srow) * (size_t)DD + (scolb >> 1);

#define STG(gbase, regionoff, kt, ks) do {                                        \
    const __hip_bfloat16* _g = (gbase) + (kt) * 64 + (ks) * 32;                   \
    char* _l = lds + (regionoff) + (((kt) & 1) * 32768) + (ks) * 16384 + tid * 16;\
    gload_lds16(_g, _l);                                                          \
    gload_lds16(_g + (size_t)128 * DD, _l + 8192);                                \
  } while (0)
#define STG_A(kt, ks) STG(gA, 0, kt, ks)
#define STG_B(kt, ks) STG(gB, 65536, kt, ks)

  // read addressing: lane reads row = base + (lane&15), 16B at swizzled col
  const int lr = lane & 15;
  const int rcol = ((lane >> 4) << 4) ^ (((lr >> 3) & 1) << 5);
  const int rbA = (wm * 128 + lr) * 64 + rcol;
  const int rbB = (wn * 64 + lr) * 64 + rcol;

#define LD8(off) (*reinterpret_cast<const short8*>(lds + (off)))
#define RD_B(BUF, KS)                                                   \
  { b[0] = LD8(65536 + (BUF) * 32768 + (KS) * 16384 + rbB + 0);         \
    b[1] = LD8(65536 + (BUF) * 32768 + (KS) * 16384 + rbB + 1024);      \
    b[2] = LD8(65536 + (BUF) * 32768 + (KS) * 16384 + rbB + 2048);      \
    b[3] = LD8(65536 + (BUF) * 32768 + (KS) * 16384 + rbB + 3072); }
#define RD_A4(BUF, KS, MH, DST)                                                   \
  { a[(DST) + 0] = LD8((BUF) * 32768 + (KS) * 16384 + rbA + (MH) * 4096 + 0);     \
    a[(DST) + 1] = LD8((BUF) * 32768 + (KS) * 16384 + rbA + (MH) * 4096 + 1024);  \
    a[(DST) + 2] = LD8((BUF) * 32768 + (KS) * 16384 + rbA + (MH) * 4096 + 2048);  \
    a[(DST) + 3] = LD8((BUF) * 32768 + (KS) * 16384 + rbA + (MH) * 4096 + 3072); }

#define BAR __builtin_amdgcn_s_barrier()
#define LGKM0 asm volatile("s_waitcnt lgkmcnt(0)" ::: "memory")
#define VM6 asm volatile("s_waitcnt vmcnt(6)" ::: "memory")

#define MFMA16(MH)                                                                \
  __builtin_amdgcn_s_setprio(1);                                                  \
  { _Pragma("unroll") for (int i = 0; i < 4; ++i) {                               \
      _Pragma("unroll") for (int n = 0; n < 4; ++n) {                             \
        acc[(MH) * 4 + i][n] = __builtin_amdgcn_mfma_f32_16x16x32_bf16(           \
            a[(MH) * 4 + i], b[n], acc[(MH) * 4 + i][n], 0, 0, 0); } } }          \
  __builtin_amdgcn_s_setprio(0);

  // one K-tile = 4 phases. reads: P1={B ks0, A mh0 ks0}, P2={A mh1 ks0},
  // P3={B ks1, A mh0 ks1, A mh1 ks1}, P4={}. stages: P1=next.B1, P2..P4 =
  // next2.{B0,A0,A1}. Every staged slot's last reader drained by the
  // preceding phase's lgkmcnt(0) -> no write-while-read hazard.
#define KTILE(BUF, TN1, TN2)            \
  RD_B(BUF, 0); RD_A4(BUF, 0, 0, 0);    \
  STG_B(TN1, 1);                        \
  BAR; LGKM0; MFMA16(0); BAR;           \
  RD_A4(BUF, 0, 1, 4);                  \
  STG_B(TN2, 0);                        \
  BAR; LGKM0; MFMA16(1); BAR;           \
  RD_B(BUF, 1); RD_A4(BUF, 1, 0, 0); RD_A4(BUF, 1, 1, 4); \
  STG_A(TN2, 0);                        \
  BAR; LGKM0; MFMA16(0); BAR;           \
  STG_A(TN2, 1); VM6;                   \
  BAR; LGKM0; MFMA16(1); BAR;

  f32x4 acc[8][4] = {};
  short8 a[8], b[4];

  // prologue: tiles 0 (all 4 halves) + 1.{B0,A0,A1}; then vmcnt(6) => tile0 done
  STG_B(0, 0); STG_A(0, 0); STG_A(0, 1); STG_B(0, 1);
  STG_B(1, 0); STG_A(1, 0); STG_A(1, 1);
  VM6;
  BAR;

  for (int kt = 0; kt < DD / 64; kt += 2) {
    const int t2 = (kt + 2 < DD / 64) ? kt + 2 : DD / 64 - 1;
    const int t3 = (kt + 3 < DD / 64) ? kt + 3 : DD / 64 - 1;
    KTILE(0, kt + 1, t2);
    KTILE(1, t2, t3);
  }

  // epilogue: C/D layout col = lane&15, row = (lane>>4)*4 + reg
  const int orow = (lane >> 4) * 4;
  const int ocol = lane & 15;
  #pragma unroll
  for (int mh = 0; mh < 2; ++mh) {
    #pragma unroll
    for (int i = 0; i < 4; ++i) {
      #pragma unroll
      for (int n = 0; n < 4; ++n) {
        #pragma unroll
        for (int jj = 0; jj < 4; ++jj) {
          size_t rrow = arow + (size_t)wm * 128 + mh * 64 + i * 16 + orow + jj;
          size_t ccol = brow + (size_t)wn * 64 + n * 16 + ocol;
          C[rrow * DD + ccol] = acc[mh * 4 + i][n][jj];
        }
      }
    }
  }
#undef STG
#undef STG_A
#undef STG_B
#undef LD8
#undef RD_B
#undef RD_A4
#undef BAR
#undef LGKM0
#undef VM6
#undef MFMA16
#undef KTILE
}

extern "C" void kernel_launch(void* const* d_in, const int* in_sizes, int n_in,
                              void* d_out, int out_size, void* d_ws, size_t ws_size,
                              hipStream_t stream) {
  const float* x = (const float*)d_in[0];
  const float* w = (const float*)d_in[1];
  float* outMM = (float*)d_out;                        // [16384][4096]
  float* outP = (float*)d_out + (size_t)NROWS * DD;    // [4096][4096]

  char* ws = (char*)d_ws;
  __hip_bfloat16* A = (__hip_bfloat16*)ws;                                   // 128MB
  __hip_bfloat16* Bt = (__hip_bfloat16*)(ws + (size_t)NROWS * DD * 2);       // 32MB
  float* r = (float*)(ws + (size_t)NROWS * DD * 2 + (size_t)DD * DD * 2);
  float* c = r + DD;
  float* pm = c + DD;
  float* ps = pm + 32 * DD;

  k_zero<<<DD / 256, 256, 0, stream>>>(c, DD);
  k_fftmag<<<NROWS, 256, 0, stream>>>(x, A);
  for (int it = 0; it < 5; ++it) {
    k_row_lse<<<DD, 256, 0, stream>>>(w, c, r);
    k_col_partial<<<dim3(16, 32), 256, 0, stream>>>(w, r, pm, ps);
    k_col_final<<<DD / 256, 256, 0, stream>>>(pm, ps, c);
  }
  k_pfinal<<<dim3(64, 64), 256, 0, stream>>>(w, r, c, outP, Bt);
  k_gemm256<<<1024, 512, 0, stream>>>(A, Bt, outMM);
}